// Round 1
// baseline (213.451 us; speedup 1.0000x reference)
//
#include <hip/hip_runtime.h>
#include <cmath>

#define HH 256
#define WW 256
#define BB 64
#define TS 32
#define RR 6
#define LTS (TS + 2*RR)   // 44

// ---------------------------------------------------------------------------
// Kernel 0: zero the per-(batch,map) max array (ws is poisoned to 0xAA)
// ---------------------------------------------------------------------------
__global__ void init_max_kernel(float* __restrict__ maxbuf) {
    int i = threadIdx.x;
    if (i < BB * 3) maxbuf[i] = 0.0f;
}

// ---------------------------------------------------------------------------
// Kernel 1: separable 13-tap Gaussian splat of binarized mask.
// One block per 32x32 output tile per (b, map). Writes UNNORMALIZED g into
// d_out channel (map+1); records per-(b,map) max via atomicMax (int trick,
// valid because g >= 0).
// map 0: target = splat(x[:,2], sigma=1.0) -> out ch1
// map 1: cost   = splat(x[:,1], sigma=1.0) -> out ch2
// map 2: hist   = splat(x[:,3], sigma=0.5) -> out ch3
// ---------------------------------------------------------------------------
__global__ __launch_bounds__(256) void splat_kernel(const float* __restrict__ x,
                                                    float* __restrict__ out,
                                                    float* __restrict__ maxbuf) {
    __shared__ float mask[LTS][LTS + 1];   // 44 x 45 (+1 pad)
    __shared__ float tmp[LTS][TS];         // 44 x 32
    __shared__ float wred[4];

    const int z = blockIdx.z;
    const int b = z / 3;
    const int m = z - 3 * b;
    const int src_c = (m == 0) ? 2 : ((m == 1) ? 1 : 3);
    const float inv2s2 = (m == 2) ? 2.0f : 0.5f;   // 1/(2 sigma^2)

    float w[RR + 1];
#pragma unroll
    for (int d = 0; d <= RR; ++d) w[d] = expf(-(float)(d * d) * inv2s2);

    const int ti0 = blockIdx.y * TS;
    const int tj0 = blockIdx.x * TS;
    const float* xc = x + ((size_t)b * 4 + src_c) * (HH * WW);
    const int tid = threadIdx.x;

    // Load binarized mask tile with halo (zero outside image)
    for (int idx = tid; idx < LTS * LTS; idx += 256) {
        int r = idx / LTS, c = idx - r * LTS;
        int gi = ti0 + r - RR;
        int gj = tj0 + c - RR;
        float v = 0.0f;
        if (gi >= 0 && gi < HH && gj >= 0 && gj < WW)
            v = (xc[gi * WW + gj] > 0.0f) ? 1.0f : 0.0f;
        mask[r][c] = v;
    }
    __syncthreads();

    // Horizontal pass
    for (int idx = tid; idx < LTS * TS; idx += 256) {
        int r = idx / TS, c = idx - r * TS;
        float s = w[0] * mask[r][c + RR];
#pragma unroll
        for (int d = 1; d <= RR; ++d)
            s += w[d] * (mask[r][c + RR - d] + mask[r][c + RR + d]);
        tmp[r][c] = s;
    }
    __syncthreads();

    // Vertical pass + write + local max
    float lmax = 0.0f;
    float* oc = out + ((size_t)b * 5 + (m + 1)) * (HH * WW);
    for (int idx = tid; idx < TS * TS; idx += 256) {
        int r = idx / TS, c = idx - r * TS;
        float s = w[0] * tmp[r + RR][c];
#pragma unroll
        for (int d = 1; d <= RR; ++d)
            s += w[d] * (tmp[r + RR - d][c] + tmp[r + RR + d][c]);
        oc[(size_t)(ti0 + r) * WW + (tj0 + c)] = s;
        lmax = fmaxf(lmax, s);
    }

    // Block max reduction: wave shuffle then LDS across 4 waves
#pragma unroll
    for (int off = 32; off > 0; off >>= 1)
        lmax = fmaxf(lmax, __shfl_down(lmax, off, 64));
    if ((tid & 63) == 0) wred[tid >> 6] = lmax;
    __syncthreads();
    if (tid == 0) {
        float bm = fmaxf(fmaxf(wred[0], wred[1]), fmaxf(wred[2], wred[3]));
        atomicMax((int*)&maxbuf[z], __float_as_int(bm));  // all values >= 0
    }
}

// ---------------------------------------------------------------------------
// Kernel 2: normalize ch1..3 in place, write ch4 = t*c, copy ch0. float4.
// ---------------------------------------------------------------------------
__global__ __launch_bounds__(256) void finalize_kernel(const float* __restrict__ x,
                                                       float* __restrict__ out,
                                                       const float* __restrict__ maxbuf) {
    const int plane4 = HH * WW / 4;          // 16384 float4 per plane
    int gid = blockIdx.x * 256 + threadIdx.x;
    int b = gid >> 14;                       // gid / 16384
    int q = gid & (plane4 - 1);

    float mt = maxbuf[b * 3 + 0]; if (mt == 0.0f) mt = 1.0f;
    float mc = maxbuf[b * 3 + 1]; if (mc == 0.0f) mc = 1.0f;
    float mh = maxbuf[b * 3 + 2]; if (mh == 0.0f) mh = 1.0f;
    float rt = 1.0f / mt, rc = 1.0f / mc, rh = 1.0f / mh;

    const float4* x0 = (const float4*)(x + (size_t)b * 4 * (HH * WW));
    float4* o = (float4*)(out + (size_t)b * 5 * (HH * WW));

    float4 c0 = x0[q];
    float4 t = o[plane4 + q];
    float4 c = o[2 * plane4 + q];
    float4 h = o[3 * plane4 + q];

    t.x *= rt; t.y *= rt; t.z *= rt; t.w *= rt;
    c.x *= rc; c.y *= rc; c.z *= rc; c.w *= rc;
    h.x *= rh; h.y *= rh; h.z *= rh; h.w *= rh;
    float4 mul = make_float4(t.x * c.x, t.y * c.y, t.z * c.z, t.w * c.w);

    o[q] = c0;
    o[plane4 + q] = t;
    o[2 * plane4 + q] = c;
    o[3 * plane4 + q] = h;
    o[4 * plane4 + q] = mul;
}

extern "C" void kernel_launch(void* const* d_in, const int* in_sizes, int n_in,
                              void* d_out, int out_size, void* d_ws, size_t ws_size,
                              hipStream_t stream) {
    const float* x = (const float*)d_in[0];
    float* out = (float*)d_out;
    float* maxbuf = (float*)d_ws;

    hipLaunchKernelGGL(init_max_kernel, dim3(1), dim3(256), 0, stream, maxbuf);

    dim3 g1(WW / TS, HH / TS, BB * 3);
    hipLaunchKernelGGL(splat_kernel, g1, dim3(256), 0, stream, x, out, maxbuf);

    int nblk = BB * HH * WW / 4 / 256;  // 4096
    hipLaunchKernelGGL(finalize_kernel, dim3(nblk), dim3(256), 0, stream, x, out, maxbuf);
}

// Round 2
// 189.355 us; speedup vs baseline: 1.1273x; 1.1273x over previous
//
#include <hip/hip_runtime.h>
#include <cmath>

#define HH 256
#define WW 256
#define BB 64
#define TSX 64
#define TSY 32
#define RR 6
#define LTSX (TSX + 2*RR)   // 76
#define LTSY (TSY + 2*RR)   // 44
#define MSTR 84             // mask LDS row stride (floats); 84*4=336 B, 16B-aligned, bank step 20
#define TSTR 68             // tmp LDS row stride (floats); 68*4=272 B, 16B-aligned, bank step 4

// ---------------------------------------------------------------------------
// Kernel 0: zero the per-(batch,map) max array (ws is poisoned to 0xAA)
// ---------------------------------------------------------------------------
__global__ void init_max_kernel(float* __restrict__ maxbuf) {
    int i = threadIdx.x;
    if (i < BB * 3) maxbuf[i] = 0.0f;
}

// ---------------------------------------------------------------------------
// Kernel 1: separable 13-tap Gaussian splat of binarized mask.
// One block per 64x32 output tile per (b, map). All LDS access is b128.
// map 0: target = splat(x[:,2], s=1.0) -> out ch1
// map 1: cost   = splat(x[:,1], s=1.0) -> out ch2
// map 2: hist   = splat(x[:,3], s=0.5) -> out ch3
// ---------------------------------------------------------------------------
__global__ __launch_bounds__(256) void splat_kernel(const float* __restrict__ x,
                                                    float* __restrict__ out,
                                                    float* __restrict__ maxbuf) {
    __shared__ float mask[LTSY * MSTR];   // 44*84*4 = 14784 B
    __shared__ float tmp[LTSY * TSTR];    // 44*68*4 = 11968 B
    __shared__ float wred[4];

    const int z = blockIdx.z;
    const int b = z / 3;
    const int m = z - 3 * b;
    const int src_c = (m == 0) ? 2 : ((m == 1) ? 1 : 3);
    const float inv2s2 = (m == 2) ? 2.0f : 0.5f;   // 1/(2 sigma^2)

    float w[RR + 1];
#pragma unroll
    for (int d = 0; d <= RR; ++d) w[d] = expf(-(float)(d * d) * inv2s2);

    const int ti0 = blockIdx.y * TSY;
    const int tj0 = blockIdx.x * TSX;
    const float* xc = x + ((size_t)b * 4 + src_c) * (HH * WW);
    const int tid = threadIdx.x;

    // ---- Load binarized mask halo tile (zero outside image), scalar writes ----
    for (int idx = tid; idx < LTSY * LTSX; idx += 256) {
        int r = idx / LTSX, c = idx - r * LTSX;
        int gi = ti0 + r - RR;
        int gj = tj0 + c - RR;
        float v = 0.0f;
        if (gi >= 0 && gi < HH && gj >= 0 && gj < WW)
            v = (xc[gi * WW + gj] > 0.0f) ? 1.0f : 0.0f;
        mask[r * MSTR + c] = v;
    }
    __syncthreads();

    // ---- Horizontal pass: 44 rows x 8 pair-units (8 outputs each) = 352 ----
    for (int idx = tid; idx < LTSY * 8; idx += 256) {
        int r = idx >> 3, up = idx & 7;
        const float4* mrow = (const float4*)&mask[r * MSTR + 8 * up];
        float4 q0 = mrow[0], q1 = mrow[1], q2 = mrow[2], q3 = mrow[3], q4 = mrow[4];
        float arr[20] = {q0.x, q0.y, q0.z, q0.w,
                         q1.x, q1.y, q1.z, q1.w,
                         q2.x, q2.y, q2.z, q2.w,
                         q3.x, q3.y, q3.z, q3.w,
                         q4.x, q4.y, q4.z, q4.w};
        float o[8];
#pragma unroll
        for (int t = 0; t < 8; ++t) {
            float s = w[6] * (arr[t] + arr[t + 12]);
            s += w[5] * (arr[t + 1] + arr[t + 11]);
            s += w[4] * (arr[t + 2] + arr[t + 10]);
            s += w[3] * (arr[t + 3] + arr[t + 9]);
            s += w[2] * (arr[t + 4] + arr[t + 8]);
            s += w[1] * (arr[t + 5] + arr[t + 7]);
            s += w[0] * arr[t + 6];
            o[t] = s;
        }
        float4* trow = (float4*)&tmp[r * TSTR + 8 * up];
        trow[0] = make_float4(o[0], o[1], o[2], o[3]);
        trow[1] = make_float4(o[4], o[5], o[6], o[7]);
    }
    __syncthreads();

    // ---- Vertical pass: each thread computes 2 row-adjacent float4 outputs ----
    // 256 threads = 16 col-groups x 16 row-pairs, exactly the 32x64 tile.
    const int u = tid & 15;          // float4 column group (cols 4u..4u+3)
    const int r0 = (tid >> 4) * 2;   // output rows r0, r0+1
    float4 a0 = make_float4(0.f, 0.f, 0.f, 0.f);
    float4 a1 = make_float4(0.f, 0.f, 0.f, 0.f);
#pragma unroll
    for (int k = 0; k < 14; ++k) {
        // tmp row (r0 + k) holds h-blurred image row (ti0 + r0 + k - 6)
        float4 v = *(const float4*)&tmp[(r0 + k) * TSTR + 4 * u];
        if (k < 13) {
            float wk = w[k < 6 ? 6 - k : k - 6];
            a0.x += wk * v.x; a0.y += wk * v.y; a0.z += wk * v.z; a0.w += wk * v.w;
        }
        if (k > 0) {
            int kk = k - 1;
            float wk = w[kk < 6 ? 6 - kk : kk - 6];
            a1.x += wk * v.x; a1.y += wk * v.y; a1.z += wk * v.z; a1.w += wk * v.w;
        }
    }

    float* oc = out + ((size_t)b * 5 + (m + 1)) * (HH * WW);
    *(float4*)&oc[(size_t)(ti0 + r0) * WW + tj0 + 4 * u] = a0;
    *(float4*)&oc[(size_t)(ti0 + r0 + 1) * WW + tj0 + 4 * u] = a1;

    float lmax = fmaxf(fmaxf(fmaxf(a0.x, a0.y), fmaxf(a0.z, a0.w)),
                       fmaxf(fmaxf(a1.x, a1.y), fmaxf(a1.z, a1.w)));

    // Block max reduction: wave shuffle then LDS across 4 waves
#pragma unroll
    for (int off = 32; off > 0; off >>= 1)
        lmax = fmaxf(lmax, __shfl_down(lmax, off, 64));
    if ((tid & 63) == 0) wred[tid >> 6] = lmax;
    __syncthreads();
    if (tid == 0) {
        float bm = fmaxf(fmaxf(wred[0], wred[1]), fmaxf(wred[2], wred[3]));
        atomicMax((int*)&maxbuf[z], __float_as_int(bm));  // all values >= 0
    }
}

// ---------------------------------------------------------------------------
// Kernel 2: normalize ch1..3 in place, write ch4 = t*c, copy ch0. float4.
// ---------------------------------------------------------------------------
__global__ __launch_bounds__(256) void finalize_kernel(const float* __restrict__ x,
                                                       float* __restrict__ out,
                                                       const float* __restrict__ maxbuf) {
    const int plane4 = HH * WW / 4;          // 16384 float4 per plane
    int gid = blockIdx.x * 256 + threadIdx.x;
    int b = gid >> 14;                       // gid / 16384
    int q = gid & (plane4 - 1);

    float mt = maxbuf[b * 3 + 0]; if (mt == 0.0f) mt = 1.0f;
    float mc = maxbuf[b * 3 + 1]; if (mc == 0.0f) mc = 1.0f;
    float mh = maxbuf[b * 3 + 2]; if (mh == 0.0f) mh = 1.0f;
    float rt = 1.0f / mt, rc = 1.0f / mc, rh = 1.0f / mh;

    const float4* x0 = (const float4*)(x + (size_t)b * 4 * (HH * WW));
    float4* o = (float4*)(out + (size_t)b * 5 * (HH * WW));

    float4 c0 = x0[q];
    float4 t = o[plane4 + q];
    float4 c = o[2 * plane4 + q];
    float4 h = o[3 * plane4 + q];

    t.x *= rt; t.y *= rt; t.z *= rt; t.w *= rt;
    c.x *= rc; c.y *= rc; c.z *= rc; c.w *= rc;
    h.x *= rh; h.y *= rh; h.z *= rh; h.w *= rh;
    float4 mul = make_float4(t.x * c.x, t.y * c.y, t.z * c.z, t.w * c.w);

    o[q] = c0;
    o[plane4 + q] = t;
    o[2 * plane4 + q] = c;
    o[3 * plane4 + q] = h;
    o[4 * plane4 + q] = mul;
}

extern "C" void kernel_launch(void* const* d_in, const int* in_sizes, int n_in,
                              void* d_out, int out_size, void* d_ws, size_t ws_size,
                              hipStream_t stream) {
    const float* x = (const float*)d_in[0];
    float* out = (float*)d_out;
    float* maxbuf = (float*)d_ws;

    hipLaunchKernelGGL(init_max_kernel, dim3(1), dim3(256), 0, stream, maxbuf);

    dim3 g1(WW / TSX, HH / TSY, BB * 3);   // 4 x 8 x 192 = 6144 blocks
    hipLaunchKernelGGL(splat_kernel, g1, dim3(256), 0, stream, x, out, maxbuf);

    int nblk = BB * HH * WW / 4 / 256;  // 4096
    hipLaunchKernelGGL(finalize_kernel, dim3(nblk), dim3(256), 0, stream, x, out, maxbuf);
}

// Round 3
// 154.943 us; speedup vs baseline: 1.3776x; 1.2221x over previous
//
#include <hip/hip_runtime.h>
#include <cmath>

#define HH 256
#define WW 256
#define BB 64
#define RR 4               // tap radius: exp(-12.5)=3.7e-6 dropped -> error ~4e-5 << 0.1 thresh
#define OROWS 16           // output rows per block
#define TROWS (OROWS + 2*RR)  // 24 h-blurred rows in LDS
#define TSTR 260           // tmp row stride (dwords): 256 + 4 -> rows rotate 4 banks

static __device__ __forceinline__ float bin(float v) { return (v > 0.0f) ? 1.0f : 0.0f; }

// ---------------------------------------------------------------------------
// Splat: separable 9-tap Gaussian of binarized mask, one block per
// (b, map, 16-row strip). h-pass straight from global (registers), tmp rows in
// LDS (all accesses full-row-contiguous b128), v-pass 4 rows/thread.
// Per-block max -> ws[z*16+strip] (no atomics).
// map 0: splat(x[:,2], s=1.0) -> out ch1 ; map 1: x[:,1] -> ch2 ; map 2: x[:,3], s=0.5 -> ch3
// ---------------------------------------------------------------------------
__global__ __launch_bounds__(256) void splat_kernel(const float* __restrict__ x,
                                                    float* __restrict__ out,
                                                    float* __restrict__ maxws) {
    __shared__ float tmp[TROWS * TSTR];   // 24*260*4 = 24960 B -> 6 blocks/CU
    __shared__ float wred[4];

    const int strip = blockIdx.x;        // 0..15
    const int z = blockIdx.y;            // 0..191 = b*3+m
    const int b = z / 3;
    const int m = z - 3 * b;
    const int src_c = (m == 0) ? 2 : ((m == 1) ? 1 : 3);
    const float inv2s2 = (m == 2) ? 2.0f : 0.5f;   // 1/(2 sigma^2)

    float w[RR + 1];
#pragma unroll
    for (int d = 0; d <= RR; ++d) w[d] = expf(-(float)(d * d) * inv2s2);

    const int ti0 = strip * OROWS;
    const float* xc = x + (((size_t)b * 4 + src_c) << 16);
    const int tid = threadIdx.x;

    // ---- h-stage: 24 rows x 32 groups (8 outputs each) = 768 tasks ----
#pragma unroll
    for (int t = 0; t < 3; ++t) {
        int idx = tid + t * 256;
        int r = idx >> 5;                // tmp row 0..23
        int g = idx & 31;                // cols 8g..8g+7
        int gi = ti0 + r - RR;           // image row
        float4 q0 = make_float4(0.f,0.f,0.f,0.f), q1 = q0, q2 = q0, q3 = q0;
        if (gi >= 0 && gi < HH) {
            const float4* row = (const float4*)(xc + ((size_t)gi << 8));
            int i0 = (g > 0) ? (2 * g - 1) : 0;
            int i3 = (g < 31) ? (2 * g + 2) : 63;
            q0 = row[i0];                // cols 8g-4..8g-1 (halo, L1 hit)
            q1 = row[2 * g];             // cols 8g..8g+3
            q2 = row[2 * g + 1];         // cols 8g+4..8g+7
            q3 = row[i3];                // cols 8g+8..8g+11 (halo, L1 hit)
            if (g == 0)  q0 = make_float4(0.f,0.f,0.f,0.f);
            if (g == 31) q3 = make_float4(0.f,0.f,0.f,0.f);
        }
        float a[16] = {bin(q0.x), bin(q0.y), bin(q0.z), bin(q0.w),
                       bin(q1.x), bin(q1.y), bin(q1.z), bin(q1.w),
                       bin(q2.x), bin(q2.y), bin(q2.z), bin(q2.w),
                       bin(q3.x), bin(q3.y), bin(q3.z), bin(q3.w)};
        float o[8];
#pragma unroll
        for (int j = 0; j < 8; ++j) {
            o[j] = w[4] * (a[j]     + a[j + 8])
                 + w[3] * (a[j + 1] + a[j + 7])
                 + w[2] * (a[j + 2] + a[j + 6])
                 + w[1] * (a[j + 3] + a[j + 5])
                 + w[0] *  a[j + 4];
        }
        float* trow = &tmp[r * TSTR + 8 * g];
        *(float4*)trow       = make_float4(o[0], o[1], o[2], o[3]);
        *(float4*)(trow + 4) = make_float4(o[4], o[5], o[6], o[7]);
    }
    __syncthreads();

    // ---- v-stage: wave gr handles out rows 4gr..4gr+3, lane c -> cols 4c..4c+3 ----
    const int c = tid & 63;
    const int gr = tid >> 6;             // 0..3 (one row-group per wave)
    float4 acc[4];
#pragma unroll
    for (int rr = 0; rr < 4; ++rr) acc[rr] = make_float4(0.f,0.f,0.f,0.f);
#pragma unroll
    for (int k = 0; k < 12; ++k) {       // tmp rows 4gr+k ; all 64 lanes same row, contiguous
        float4 v = *(const float4*)&tmp[(4 * gr + k) * TSTR + 4 * c];
#pragma unroll
        for (int rr = 0; rr < 4; ++rr) {
            int d = k - RR - rr;
            if (d >= -RR && d <= RR) {
                float wk = w[d < 0 ? -d : d];
                acc[rr].x += wk * v.x; acc[rr].y += wk * v.y;
                acc[rr].z += wk * v.z; acc[rr].w += wk * v.w;
            }
        }
    }

    float* oc = out + (((size_t)b * 5 + (m + 1)) << 16);
    float lmax = 0.0f;
#pragma unroll
    for (int rr = 0; rr < 4; ++rr) {
        int row = ti0 + 4 * gr + rr;
        *(float4*)&oc[((size_t)row << 8) + 4 * c] = acc[rr];
        lmax = fmaxf(lmax, fmaxf(fmaxf(acc[rr].x, acc[rr].y), fmaxf(acc[rr].z, acc[rr].w)));
    }

#pragma unroll
    for (int off = 32; off > 0; off >>= 1)
        lmax = fmaxf(lmax, __shfl_down(lmax, off, 64));
    if ((tid & 63) == 0) wred[tid >> 6] = lmax;
    __syncthreads();
    if (tid == 0)
        maxws[z * 16 + strip] = fmaxf(fmaxf(wred[0], wred[1]), fmaxf(wred[2], wred[3]));
}

// ---------------------------------------------------------------------------
// Finalize: reduce 48 strip-maxes per batch, normalize ch1..3 in place,
// write ch4 = t*c, copy ch0. One block per (b, 1/8 plane slab). float4.
// ---------------------------------------------------------------------------
__global__ __launch_bounds__(256) void finalize_kernel(const float* __restrict__ x,
                                                       float* __restrict__ out,
                                                       const float* __restrict__ maxws) {
    __shared__ float lds[48];
    const int b = blockIdx.x >> 3;
    const int slab = blockIdx.x & 7;
    const int tid = threadIdx.x;

    if (tid < 48) lds[tid] = maxws[b * 48 + tid];   // [m*16 + strip]
    __syncthreads();

    float mt = 0.f, mc = 0.f, mh = 0.f;
#pragma unroll
    for (int s = 0; s < 16; ++s) {                  // broadcast reads (same addr all lanes)
        mt = fmaxf(mt, lds[s]);
        mc = fmaxf(mc, lds[16 + s]);
        mh = fmaxf(mh, lds[32 + s]);
    }
    if (mt == 0.f) mt = 1.f;
    if (mc == 0.f) mc = 1.f;
    if (mh == 0.f) mh = 1.f;
    const float rt = 1.f / mt, rc = 1.f / mc, rh = 1.f / mh;

    const int plane4 = HH * WW / 4;                 // 16384
    const float4* x0 = (const float4*)(x + ((size_t)b * 4 << 16));
    float4* o = (float4*)(out + ((size_t)b * 5 << 16));

#pragma unroll
    for (int i = 0; i < 8; ++i) {
        int q = slab * 2048 + i * 256 + tid;
        float4 c0 = x0[q];
        float4 t = o[plane4 + q];
        float4 c = o[2 * plane4 + q];
        float4 h = o[3 * plane4 + q];
        t.x *= rt; t.y *= rt; t.z *= rt; t.w *= rt;
        c.x *= rc; c.y *= rc; c.z *= rc; c.w *= rc;
        h.x *= rh; h.y *= rh; h.z *= rh; h.w *= rh;
        float4 mul = make_float4(t.x * c.x, t.y * c.y, t.z * c.z, t.w * c.w);
        o[q] = c0;
        o[plane4 + q] = t;
        o[2 * plane4 + q] = c;
        o[3 * plane4 + q] = h;
        o[4 * plane4 + q] = mul;
    }
}

extern "C" void kernel_launch(void* const* d_in, const int* in_sizes, int n_in,
                              void* d_out, int out_size, void* d_ws, size_t ws_size,
                              hipStream_t stream) {
    const float* x = (const float*)d_in[0];
    float* out = (float*)d_out;
    float* maxws = (float*)d_ws;   // 192*16 floats = 12 KB block maxes

    dim3 g1(HH / OROWS, BB * 3);   // 16 strips x 192 (b,map) = 3072 blocks
    hipLaunchKernelGGL(splat_kernel, g1, dim3(256), 0, stream, x, out, maxws);

    hipLaunchKernelGGL(finalize_kernel, dim3(BB * 8), dim3(256), 0, stream, x, out, maxws);
}